// Round 10
// baseline (73.845 us; speedup 1.0000x reference)
//
#include <hip/hip_runtime.h>
#include <hip/hip_bf16.h>

#define B_ 32
#define L_ 2048
#define E_ 256
#define H_ 256
#define MAXSTEP 20
#define NLW 4     // l's per block
#define NCH 26    // ceil(103/NLW)
#define NGRP (MAXSTEP * NCH)   // 520 blocks x 4 waves

typedef __attribute__((ext_vector_type(4))) float f32x4;
typedef __attribute__((ext_vector_type(8))) short bf16x8;
using bf16 = __hip_bfloat16;

__device__ inline short cvt1(float x) {
    bf16 b = __float2bfloat16(x);
    return *reinterpret_cast<short*>(&b);
}

// Transpose + convert: cnn fp32 [s][e][h] -> wt bf16 [s][h][e] (K-contiguous B operand).
__global__ void transpose_w_kernel(const float* __restrict__ cnn, short* __restrict__ wt) {
    __shared__ short tile[32][33];
    const int s  = blockIdx.z;
    const int e0 = blockIdx.y * 32;
    const int h0 = blockIdx.x * 32;
    const int tx = threadIdx.x;
    const int ty = threadIdx.y;
    const float* src = cnn + ((size_t)s * E_ + e0) * H_ + h0;
#pragma unroll
    for (int i = ty; i < 32; i += 8)
        tile[i][tx] = cvt1(src[(size_t)i * H_ + tx]);
    __syncthreads();
    short* dst = wt + ((size_t)s * H_ + h0) * E_ + e0;
#pragma unroll
    for (int i = ty; i < 32; i += 8)
        dst[(size_t)i * E_ + tx] = tile[tx][i];
}

// Registers-only pipeline. Block = (s, chunk): 4 waves, wave wv owns columns
// [wv*64, wv*64+64) of out[0:32, l, :] for NLW same-s l's. NO LDS, NO barriers:
// each wave is an independent pipeline. B (W^T[s], 64 h-rows) in 128 VGPRs.
// A-fragments loaded straight to registers, software-pipelined 1 kstep ahead;
// sched_barrier(0) after each load-issue group pins the issue point (prevents
// the RA from sinking loads back to their use — the R2/R3 failure mode).
// All loops fully unrolled -> all abuf indices compile-time (no scratch).
// 4x A-redundancy across the 4 sibling waves is same-CU -> same-XCD L2.
// mfma_f32_16x16x32_bf16: A row=lane&15, k=(lane>>4)*8+j; B col=lane&15;
// C/D col=lane&15, row=(lane>>4)*4+reg.
__global__ __launch_bounds__(256, 2) void vaw_reg_kernel(
        const float* __restrict__ A, const short* __restrict__ Wt,
        float* __restrict__ out) {
    const int g_    = blockIdx.x;
    const int s     = g_ / NCH;
    const int chunk = g_ % NCH;
    const int cnt   = (s < 8) ? 103 : 102;   // #{l < 2048 : l % 20 == s}
    const int wv    = threadIdx.x >> 6;
    const int lane  = threadIdx.x & 63;
    const int r     = lane & 15;
    const int g     = lane >> 4;
    const int nbase = wv * 64;

    int lv[NLW];
#pragma unroll
    for (int il = 0; il < NLW; ++il) {
        int idx = chunk * NLW + il;
        if (idx > cnt - 1) idx = cnt - 1;    // tail clamp: duplicate work, benign
        lv[il] = s + 20 * idx;
    }

    // A-fragment loader: 4 x dwordx4 for one kstep (rows r and r+16).
    auto loadk = [&](f32x4* dst, int l, int kk) {
        const float* p0 = A + ((size_t)r * L_ + l) * E_ + g * 8 + kk * 32;
        const float* p1 = A + ((size_t)(r + 16) * L_ + l) * E_ + g * 8 + kk * 32;
        dst[0] = *(const f32x4*)p0;
        dst[1] = *(const f32x4*)(p0 + 4);
        dst[2] = *(const f32x4*)p1;
        dst[3] = *(const f32x4*)(p1 + 4);
    };

    f32x4 abuf[2][4];
    loadk(abuf[0], lv[0], 0);                // prologue: first kstep in flight

    // ---- B into registers: breg[kk][nf], 32 x 16B loads (L2/L3-resident Wt).
    const short* wtb = Wt + ((size_t)s * H_ + nbase + r) * E_ + g * 8;
    bf16x8 breg[8][4];
#pragma unroll
    for (int kk = 0; kk < 8; ++kk)
#pragma unroll
        for (int nf = 0; nf < 4; ++nf)
            breg[kk][nf] = *(const bf16x8*)(wtb + (size_t)nf * 16 * E_ + kk * 32);

#pragma unroll
    for (int il = 0; il < NLW; ++il) {
        const int l = lv[il];
        f32x4 acc[2][4];
#pragma unroll
        for (int mf = 0; mf < 2; ++mf)
#pragma unroll
            for (int nf = 0; nf < 4; ++nf)
                acc[mf][nf] = f32x4{0.f, 0.f, 0.f, 0.f};

#pragma unroll
        for (int kk = 0; kk < 8; ++kk) {
            const int t  = il * 8 + kk;      // flat phase 0..31 (compile-time)
            const int cb = t & 1;
            if (t < NLW * 8 - 1) {
                const int tn = t + 1;
                loadk(abuf[cb ^ 1], lv[tn >> 3], tn & 7);   // issue next kstep
            }
            __builtin_amdgcn_sched_barrier(0);               // pin issue point

            bf16x8 a0, a1;
#pragma unroll
            for (int j = 0; j < 4; ++j) {
                a0[j]     = cvt1(abuf[cb][0][j]);
                a0[j + 4] = cvt1(abuf[cb][1][j]);
                a1[j]     = cvt1(abuf[cb][2][j]);
                a1[j + 4] = cvt1(abuf[cb][3][j]);
            }
#pragma unroll
            for (int nf = 0; nf < 4; ++nf) {
                acc[0][nf] = __builtin_amdgcn_mfma_f32_16x16x32_bf16(a0, breg[kk][nf], acc[0][nf], 0, 0, 0);
                acc[1][nf] = __builtin_amdgcn_mfma_f32_16x16x32_bf16(a1, breg[kk][nf], acc[1][nf], 0, 0, 0);
            }
        }

        const int row0 = g * 4;
#pragma unroll
        for (int mf = 0; mf < 2; ++mf) {
#pragma unroll
            for (int nf = 0; nf < 4; ++nf) {
                const int h = nbase + nf * 16 + r;
#pragma unroll
                for (int i = 0; i < 4; ++i) {
                    const int bb = mf * 16 + row0 + i;
                    out[((size_t)bb * L_ + l) * H_ + h] = acc[mf][nf][i];
                }
            }
        }
        if (l == L_ - 1) {
            float* out2 = out + (size_t)B_ * L_ * H_;
#pragma unroll
            for (int mf = 0; mf < 2; ++mf)
#pragma unroll
                for (int nf = 0; nf < 4; ++nf) {
                    const int h = nbase + nf * 16 + r;
#pragma unroll
                    for (int i = 0; i < 4; ++i) {
                        const int bb = mf * 16 + row0 + i;
                        out2[(size_t)bb * H_ + h] = acc[mf][nf][i];
                    }
                }
        }
    }
}

// Fallback (no workspace): round-5 structure, B from fp32 cnn per k-step.
__global__ __launch_bounds__(256) void vaw_fallback_kernel(
        const float* __restrict__ A, const float* __restrict__ W, float* __restrict__ out) {
    __shared__ __align__(16) float aLds[2][B_ * E_];
    const int l0   = blockIdx.x * 4;
    const int wv   = threadIdx.x >> 6;
    const int lane = threadIdx.x & 63;
    const int r    = lane & 15;
    const int g    = lane >> 4;
    const int nbase = wv * 64;
    const int key   = r & 7;

    auto stage = [&](int it) {
        float* dst = aLds[it & 1];
        const int l = l0 + it;
#pragma unroll
        for (int t = 0; t < 8; ++t) {
            const int b  = t * 4 + wv;
            const int cgx = lane ^ (b & 7);
            const float* gp = A + ((size_t)b * L_ + l) * E_ + cgx * 4;
            __builtin_amdgcn_global_load_lds(
                (const __attribute__((address_space(1))) void*)gp,
                (__attribute__((address_space(3))) void*)&dst[b * 256],
                16, 0, 0);
        }
    };

    stage(0);
#pragma unroll 1
    for (int it = 0; it < 4; ++it) {
        const int l   = l0 + it;
        const int sidx = l % MAXSTEP;
        const int cur = it & 1;
        if (it < 3) {
            stage(it + 1);
            asm volatile("s_waitcnt vmcnt(8)" ::: "memory");
        } else {
            asm volatile("s_waitcnt vmcnt(0)" ::: "memory");
        }
        __builtin_amdgcn_s_barrier();
        __builtin_amdgcn_sched_barrier(0);

        f32x4 acc[2][4] = {};
        const float* Wf = W + (size_t)sidx * E_ * H_;
#pragma unroll 2
        for (int kk = 0; kk < 8; ++kk) {
            const int k0 = kk * 32;
            const int c0 = kk * 8 + g * 2;
            f32x4 a0lo = *(const f32x4*)&aLds[cur][r * 256 + ((c0 ^ key) << 2)];
            f32x4 a0hi = *(const f32x4*)&aLds[cur][r * 256 + (((c0 + 1) ^ key) << 2)];
            f32x4 a1lo = *(const f32x4*)&aLds[cur][(r + 16) * 256 + ((c0 ^ key) << 2)];
            f32x4 a1hi = *(const f32x4*)&aLds[cur][(r + 16) * 256 + (((c0 + 1) ^ key) << 2)];
            bf16x8 a0, a1;
#pragma unroll
            for (int j = 0; j < 4; ++j) {
                a0[j]     = cvt1(a0lo[j]);
                a0[j + 4] = cvt1(a0hi[j]);
                a1[j]     = cvt1(a1lo[j]);
                a1[j + 4] = cvt1(a1hi[j]);
            }
            bf16x8 b0, b1, b2, b3;
#pragma unroll
            for (int j = 0; j < 8; ++j) {
                const size_t krow = (size_t)(k0 + g * 8 + j) * H_;
                b0[j] = cvt1(Wf[krow + nbase +  0 + r]);
                b1[j] = cvt1(Wf[krow + nbase + 16 + r]);
                b2[j] = cvt1(Wf[krow + nbase + 32 + r]);
                b3[j] = cvt1(Wf[krow + nbase + 48 + r]);
            }
            acc[0][0] = __builtin_amdgcn_mfma_f32_16x16x32_bf16(a0, b0, acc[0][0], 0, 0, 0);
            acc[0][1] = __builtin_amdgcn_mfma_f32_16x16x32_bf16(a0, b1, acc[0][1], 0, 0, 0);
            acc[0][2] = __builtin_amdgcn_mfma_f32_16x16x32_bf16(a0, b2, acc[0][2], 0, 0, 0);
            acc[0][3] = __builtin_amdgcn_mfma_f32_16x16x32_bf16(a0, b3, acc[0][3], 0, 0, 0);
            acc[1][0] = __builtin_amdgcn_mfma_f32_16x16x32_bf16(a1, b0, acc[1][0], 0, 0, 0);
            acc[1][1] = __builtin_amdgcn_mfma_f32_16x16x32_bf16(a1, b1, acc[1][1], 0, 0, 0);
            acc[1][2] = __builtin_amdgcn_mfma_f32_16x16x32_bf16(a1, b2, acc[1][2], 0, 0, 0);
            acc[1][3] = __builtin_amdgcn_mfma_f32_16x16x32_bf16(a1, b3, acc[1][3], 0, 0, 0);
        }

        const int row0 = g * 4;
#pragma unroll
        for (int mf = 0; mf < 2; ++mf)
#pragma unroll
            for (int nf = 0; nf < 4; ++nf) {
                const int h = nbase + nf * 16 + r;
#pragma unroll
                for (int i = 0; i < 4; ++i) {
                    const int bb = mf * 16 + row0 + i;
                    out[((size_t)bb * L_ + l) * H_ + h] = acc[mf][nf][i];
                }
            }
        if (l == L_ - 1) {
            float* out2 = out + (size_t)B_ * L_ * H_;
#pragma unroll
            for (int mf = 0; mf < 2; ++mf)
#pragma unroll
                for (int nf = 0; nf < 4; ++nf) {
                    const int h = nbase + nf * 16 + r;
#pragma unroll
                    for (int i = 0; i < 4; ++i) {
                        const int bb = mf * 16 + row0 + i;
                        out2[(size_t)bb * H_ + h] = acc[mf][nf][i];
                    }
                }
        }
        __builtin_amdgcn_s_barrier();
    }
}

extern "C" void kernel_launch(void* const* d_in, const int* in_sizes, int n_in,
                              void* d_out, int out_size, void* d_ws, size_t ws_size,
                              hipStream_t stream) {
    const float* word_rep = (const float*)d_in[0];
    const float* cnn      = (const float*)d_in[1];
    float* out = (float*)d_out;

    const size_t wt_bytes = (size_t)MAXSTEP * E_ * H_ * sizeof(short);
    if (ws_size >= wt_bytes) {
        short* wt = (short*)d_ws;
        transpose_w_kernel<<<dim3(8, 8, 20), dim3(32, 8), 0, stream>>>(cnn, wt);
        vaw_reg_kernel<<<dim3(NGRP), dim3(256), 0, stream>>>(word_rep, wt, out);
    } else {
        vaw_fallback_kernel<<<dim3(L_ / 4), dim3(256), 0, stream>>>(word_rep, cnn, out);
    }
}

// Round 11
// 55.854 us; speedup vs baseline: 1.3221x; 1.3221x over previous
//
#include <hip/hip_runtime.h>
#include <hip/hip_bf16.h>

#define B_ 32
#define L_ 2048
#define E_ 256
#define H_ 256
#define MAXSTEP 20
#define NL 4      // l's per block
#define NCH 26    // ceil(103/NL)
#define NGRP (MAXSTEP * NCH)   // 520 blocks x 8 waves

typedef __attribute__((ext_vector_type(4))) float f32x4;
typedef __attribute__((ext_vector_type(8))) short bf16x8;
using bf16 = __hip_bfloat16;

__device__ inline short cvt1(float x) {
    bf16 b = __float2bfloat16(x);
    return *reinterpret_cast<short*>(&b);
}

// Transpose + convert: cnn fp32 [s][e][h] -> wt bf16 [s][h][e] (K-contiguous B operand).
__global__ void transpose_w_kernel(const float* __restrict__ cnn, short* __restrict__ wt) {
    __shared__ short tile[32][33];
    const int s  = blockIdx.z;
    const int e0 = blockIdx.y * 32;
    const int h0 = blockIdx.x * 32;
    const int tx = threadIdx.x;
    const int ty = threadIdx.y;
    const float* src = cnn + ((size_t)s * E_ + e0) * H_ + h0;
#pragma unroll
    for (int i = ty; i < 32; i += 8)
        tile[i][tx] = cvt1(src[(size_t)i * H_ + tx]);
    __syncthreads();
    short* dst = wt + ((size_t)s * H_ + h0) * E_ + e0;
#pragma unroll
    for (int i = ty; i < 32; i += 8)
        dst[(size_t)i * E_ + tx] = tile[tx][i];
}

// Occupancy-first same-s blocks: 512 threads = 8 waves; wave wv owns the full
// 32 rows x cols [wv*32, wv*32+32) -> breg[8][2] = 64 VGPR (half of R6), so
// with __launch_bounds__(512,4) the RA must fit 128 VGPR -> 4 waves/SIMD; LDS
// 2x32KB -> 2 blocks/CU -> 16 waves/CU (2x the R6 ceiling). A (32x256 fp32,
// 32 KB/l) double-buffered via global_load_lds; counted vmcnt per wave.
// Per-wave vmem stream: stage=4 ops/tile, stores=16/l, breg=16 (prologue).
// Queue at the wait of iter it (in-order; breg drained by compiler before
// its first MFMA use in it0):
//   it0: [s0:4|s1:4|breg:16] -> retire s0 -> vmcnt(20)
//   it1: [s1:4|st0:16|s2:4]  -> vmcnt(20)
//   it2: [s2:4|st1:16|s3:4]  -> vmcnt(20)
//   it3: [s3:4|st2:16]       -> vmcnt(16)
// (l==2047 block: +16 out2 stores -> later waits only over-wait; correct.)
// LDS swizzle: row-major [32][256] floats; 16B chunk c of row stored at LDS
// chunk c^(row&7) via swizzled GLOBAL source (dest linear, rule #21); reads
// use the same XOR -> per-b128-read banks spread optimally (8 lanes per
// 4-bank group = inherent minimum).
// mfma_f32_16x16x32_bf16: A row=lane&15, k=(lane>>4)*8+j; B col=lane&15;
// C/D col=lane&15, row=(lane>>4)*4+reg.
__global__ __launch_bounds__(512, 4) void vaw_occ_kernel(
        const float* __restrict__ A, const short* __restrict__ Wt,
        float* __restrict__ out) {
    __shared__ __align__(16) float aLds[2][B_ * E_];   // 2 x 32 KB

    const int g_    = blockIdx.x;
    const int s     = g_ / NCH;
    const int chunk = g_ % NCH;
    const int cnt   = (s < 8) ? 103 : 102;   // #{l < 2048 : l % 20 == s}
    const int wv    = threadIdx.x >> 6;      // 0..7 column group (32 cols)
    const int lane  = threadIdx.x & 63;
    const int r     = lane & 15;
    const int g     = lane >> 4;
    const int nbase = wv * 32;
    const int key   = r & 7;                 // (r+16)&7 == r&7

    auto lof = [&](int il) {
        int idx = chunk * NL + il;
        if (idx > cnt - 1) idx = cnt - 1;    // tail clamp: duplicate work, benign
        return s + 20 * idx;
    };

    // Stage A-tile for iter it into aLds[it&1]: 32 ops x 1 KB (1 row each);
    // wave wv stages rows wv, wv+8, wv+16, wv+24. Lane covers 16-B chunk
    // `lane`; global source chunk = lane ^ (row&7) (inverse-swizzled source).
    auto stage = [&](int it) {
        const int l = lof(it);
        float* dst = aLds[it & 1];
#pragma unroll
        for (int j = 0; j < 4; ++j) {
            const int row = wv + j * 8;
            const int cg  = lane ^ (row & 7);
            const float* gp = A + ((size_t)row * L_ + l) * E_ + cg * 4;
            __builtin_amdgcn_global_load_lds(
                (const __attribute__((address_space(1))) void*)gp,
                (__attribute__((address_space(3))) void*)&dst[row * 256],
                16, 0, 0);
        }
    };

    stage(0);
    stage(1);

    // ---- B into registers: breg[kk][nf] (cols nbase+nf*16+r), 16 x 16B loads.
    const short* wtb = Wt + ((size_t)s * H_ + nbase + r) * E_ + g * 8;
    bf16x8 breg[8][2];
#pragma unroll
    for (int kk = 0; kk < 8; ++kk)
#pragma unroll
        for (int nf = 0; nf < 2; ++nf)
            breg[kk][nf] = *(const bf16x8*)(wtb + (size_t)nf * 16 * E_ + kk * 32);

#pragma unroll 1
    for (int it = 0; it < NL; ++it) {
        const int l   = lof(it);
        const int cur = it & 1;

        if (it < NL - 1 && it >= 1) stage(it + 1);   // s2 at it1, s3 at it2

        if (it < NL - 1) asm volatile("s_waitcnt vmcnt(20)" ::: "memory");
        else             asm volatile("s_waitcnt vmcnt(16)" ::: "memory");
        __builtin_amdgcn_s_barrier();        // all waves' stage(it) landed
        __builtin_amdgcn_sched_barrier(0);

        f32x4 acc[2][2];
#pragma unroll
        for (int mf = 0; mf < 2; ++mf)
#pragma unroll
            for (int nf = 0; nf < 2; ++nf)
                acc[mf][nf] = f32x4{0.f, 0.f, 0.f, 0.f};

#pragma unroll
        for (int kk = 0; kk < 8; ++kk) {
            const int c0 = kk * 8 + g * 2;
            f32x4 a0lo = *(const f32x4*)&aLds[cur][r * 256 + ((c0 ^ key) << 2)];
            f32x4 a0hi = *(const f32x4*)&aLds[cur][r * 256 + (((c0 + 1) ^ key) << 2)];
            f32x4 a1lo = *(const f32x4*)&aLds[cur][(r + 16) * 256 + ((c0 ^ key) << 2)];
            f32x4 a1hi = *(const f32x4*)&aLds[cur][(r + 16) * 256 + (((c0 + 1) ^ key) << 2)];
            bf16x8 a0, a1;
#pragma unroll
            for (int j = 0; j < 4; ++j) {
                a0[j]     = cvt1(a0lo[j]);
                a0[j + 4] = cvt1(a0hi[j]);
                a1[j]     = cvt1(a1lo[j]);
                a1[j + 4] = cvt1(a1hi[j]);
            }
#pragma unroll
            for (int nf = 0; nf < 2; ++nf) {
                acc[0][nf] = __builtin_amdgcn_mfma_f32_16x16x32_bf16(a0, breg[kk][nf], acc[0][nf], 0, 0, 0);
                acc[1][nf] = __builtin_amdgcn_mfma_f32_16x16x32_bf16(a1, breg[kk][nf], acc[1][nf], 0, 0, 0);
            }
        }

        const int row0 = g * 4;
#pragma unroll
        for (int mf = 0; mf < 2; ++mf) {
#pragma unroll
            for (int nf = 0; nf < 2; ++nf) {
                const int h = nbase + nf * 16 + r;
#pragma unroll
                for (int i = 0; i < 4; ++i) {
                    const int bb = mf * 16 + row0 + i;
                    out[((size_t)bb * L_ + l) * H_ + h] = acc[mf][nf][i];
                }
            }
        }
        if (l == L_ - 1) {
            float* out2 = out + (size_t)B_ * L_ * H_;
#pragma unroll
            for (int mf = 0; mf < 2; ++mf)
#pragma unroll
                for (int nf = 0; nf < 2; ++nf) {
                    const int h = nbase + nf * 16 + r;
#pragma unroll
                    for (int i = 0; i < 4; ++i) {
                        const int bb = mf * 16 + row0 + i;
                        out2[(size_t)bb * H_ + h] = acc[mf][nf][i];
                    }
                }
        }

        __builtin_amdgcn_s_barrier();   // reads of buf[cur] done before overwrite
    }
}

// Fallback (no workspace): round-5 structure, B from fp32 cnn per k-step.
__global__ __launch_bounds__(256) void vaw_fallback_kernel(
        const float* __restrict__ A, const float* __restrict__ W, float* __restrict__ out) {
    __shared__ __align__(16) float aLds[2][B_ * E_];
    const int l0   = blockIdx.x * 4;
    const int wv   = threadIdx.x >> 6;
    const int lane = threadIdx.x & 63;
    const int r    = lane & 15;
    const int g    = lane >> 4;
    const int nbase = wv * 64;
    const int key   = r & 7;

    auto stage = [&](int it) {
        float* dst = aLds[it & 1];
        const int l = l0 + it;
#pragma unroll
        for (int t = 0; t < 8; ++t) {
            const int b  = t * 4 + wv;
            const int cgx = lane ^ (b & 7);
            const float* gp = A + ((size_t)b * L_ + l) * E_ + cgx * 4;
            __builtin_amdgcn_global_load_lds(
                (const __attribute__((address_space(1))) void*)gp,
                (__attribute__((address_space(3))) void*)&dst[b * 256],
                16, 0, 0);
        }
    };

    stage(0);
#pragma unroll 1
    for (int it = 0; it < 4; ++it) {
        const int l   = l0 + it;
        const int sidx = l % MAXSTEP;
        const int cur = it & 1;
        if (it < 3) {
            stage(it + 1);
            asm volatile("s_waitcnt vmcnt(8)" ::: "memory");
        } else {
            asm volatile("s_waitcnt vmcnt(0)" ::: "memory");
        }
        __builtin_amdgcn_s_barrier();
        __builtin_amdgcn_sched_barrier(0);

        f32x4 acc[2][4] = {};
        const float* Wf = W + (size_t)sidx * E_ * H_;
#pragma unroll 2
        for (int kk = 0; kk < 8; ++kk) {
            const int k0 = kk * 32;
            const int c0 = kk * 8 + g * 2;
            f32x4 a0lo = *(const f32x4*)&aLds[cur][r * 256 + ((c0 ^ key) << 2)];
            f32x4 a0hi = *(const f32x4*)&aLds[cur][r * 256 + (((c0 + 1) ^ key) << 2)];
            f32x4 a1lo = *(const f32x4*)&aLds[cur][(r + 16) * 256 + ((c0 ^ key) << 2)];
            f32x4 a1hi = *(const f32x4*)&aLds[cur][(r + 16) * 256 + (((c0 + 1) ^ key) << 2)];
            bf16x8 a0, a1;
#pragma unroll
            for (int j = 0; j < 4; ++j) {
                a0[j]     = cvt1(a0lo[j]);
                a0[j + 4] = cvt1(a0hi[j]);
                a1[j]     = cvt1(a1lo[j]);
                a1[j + 4] = cvt1(a1hi[j]);
            }
            bf16x8 b0, b1, b2, b3;
#pragma unroll
            for (int j = 0; j < 8; ++j) {
                const size_t krow = (size_t)(k0 + g * 8 + j) * H_;
                b0[j] = cvt1(Wf[krow + nbase +  0 + r]);
                b1[j] = cvt1(Wf[krow + nbase + 16 + r]);
                b2[j] = cvt1(Wf[krow + nbase + 32 + r]);
                b3[j] = cvt1(Wf[krow + nbase + 48 + r]);
            }
            acc[0][0] = __builtin_amdgcn_mfma_f32_16x16x32_bf16(a0, b0, acc[0][0], 0, 0, 0);
            acc[0][1] = __builtin_amdgcn_mfma_f32_16x16x32_bf16(a0, b1, acc[0][1], 0, 0, 0);
            acc[0][2] = __builtin_amdgcn_mfma_f32_16x16x32_bf16(a0, b2, acc[0][2], 0, 0, 0);
            acc[0][3] = __builtin_amdgcn_mfma_f32_16x16x32_bf16(a0, b3, acc[0][3], 0, 0, 0);
            acc[1][0] = __builtin_amdgcn_mfma_f32_16x16x32_bf16(a1, b0, acc[1][0], 0, 0, 0);
            acc[1][1] = __builtin_amdgcn_mfma_f32_16x16x32_bf16(a1, b1, acc[1][1], 0, 0, 0);
            acc[1][2] = __builtin_amdgcn_mfma_f32_16x16x32_bf16(a1, b2, acc[1][2], 0, 0, 0);
            acc[1][3] = __builtin_amdgcn_mfma_f32_16x16x32_bf16(a1, b3, acc[1][3], 0, 0, 0);
        }

        const int row0 = g * 4;
#pragma unroll
        for (int mf = 0; mf < 2; ++mf)
#pragma unroll
            for (int nf = 0; nf < 4; ++nf) {
                const int h = nbase + nf * 16 + r;
#pragma unroll
                for (int i = 0; i < 4; ++i) {
                    const int bb = mf * 16 + row0 + i;
                    out[((size_t)bb * L_ + l) * H_ + h] = acc[mf][nf][i];
                }
            }
        if (l == L_ - 1) {
            float* out2 = out + (size_t)B_ * L_ * H_;
#pragma unroll
            for (int mf = 0; mf < 2; ++mf)
#pragma unroll
                for (int nf = 0; nf < 4; ++nf) {
                    const int h = nbase + nf * 16 + r;
#pragma unroll
                    for (int i = 0; i < 4; ++i) {
                        const int bb = mf * 16 + row0 + i;
                        out2[(size_t)bb * H_ + h] = acc[mf][nf][i];
                    }
                }
        }
        __builtin_amdgcn_s_barrier();
    }
}

extern "C" void kernel_launch(void* const* d_in, const int* in_sizes, int n_in,
                              void* d_out, int out_size, void* d_ws, size_t ws_size,
                              hipStream_t stream) {
    const float* word_rep = (const float*)d_in[0];
    const float* cnn      = (const float*)d_in[1];
    float* out = (float*)d_out;

    const size_t wt_bytes = (size_t)MAXSTEP * E_ * H_ * sizeof(short);
    if (ws_size >= wt_bytes) {
        short* wt = (short*)d_ws;
        transpose_w_kernel<<<dim3(8, 8, 20), dim3(32, 8), 0, stream>>>(cnn, wt);
        vaw_occ_kernel<<<dim3(NGRP), dim3(512), 0, stream>>>(word_rep, wt, out);
    } else {
        vaw_fallback_kernel<<<dim3(L_ / 4), dim3(256), 0, stream>>>(word_rep, cnn, out);
    }
}

// Round 12
// 46.719 us; speedup vs baseline: 1.5806x; 1.1955x over previous
//
#include <hip/hip_runtime.h>
#include <hip/hip_bf16.h>

#define B_ 32
#define L_ 2048
#define E_ 256
#define H_ 256
#define MAXSTEP 20
#define NL 4      // l's per block
#define NCH 26    // ceil(103/NL)
#define NGRP (MAXSTEP * NCH)   // 520 blocks x 4 waves

typedef __attribute__((ext_vector_type(4))) float f32x4;
typedef __attribute__((ext_vector_type(8))) short bf16x8;
using bf16 = __hip_bfloat16;

__device__ inline short cvt1(float x) {
    bf16 b = __float2bfloat16(x);
    return *reinterpret_cast<short*>(&b);
}

// Transpose + convert: cnn fp32 [s][e][h] -> wt bf16 [s][h][e] (K-contiguous).
__global__ void transpose_w_kernel(const float* __restrict__ cnn, short* __restrict__ wt) {
    __shared__ short tile[32][33];
    const int s  = blockIdx.z;
    const int e0 = blockIdx.y * 32;
    const int h0 = blockIdx.x * 32;
    const int tx = threadIdx.x;
    const int ty = threadIdx.y;
    const float* src = cnn + ((size_t)s * E_ + e0) * H_ + h0;
#pragma unroll
    for (int i = ty; i < 32; i += 8)
        tile[i][tx] = cvt1(src[(size_t)i * H_ + tx]);
    __syncthreads();
    short* dst = wt + ((size_t)s * H_ + h0) * E_ + e0;
#pragma unroll
    for (int i = ty; i < 32; i += 8)
        dst[(size_t)i * E_ + tx] = tile[tx][i];
}

// R6 skeleton + SWAPPED-OPERAND MFMA for coalesced 16B stores.
// Block = (s, chunk), 4 waves; wave wv owns cols [wv*64, wv*64+64) for NL
// same-s l's. B (W^T[s]) in 128 VGPRs, loaded FIRST (so its queue entries are
// oldest and drain with it0's wait). A (32x256 fp32, 32 KB) double-buffered
// via global_load_lds (source XOR-swizzled per 16B chunk, LDS dest linear,
// reads use the same XOR).
//
// Swapped mfma: D = mfma(W^T-frag [A-op, rows=h], wordrep-frag [B-op, cols=b]).
//   A-op lane(r,g): wt[s][nbase+nf*16+r][kk*32+g*8+j]  == breg[kk][nf] (as before)
//   B-op lane(r,g): word_rep[b=r(+16)][l][kk*32+g*8+j] == a0/a1 (as before)
//   D lane(r,g) reg i = out[b=r+16*half][l][nbase+nf*16+g*4+i]
//   -> 4 consecutive h per lane = one global_store_dwordx4 (8 stores/wave/l,
//      was 32 scattered dwords).
// Per-wave vmem queue (stage=8/tile, stores=8/l, breg=32 prologue):
//   it0: [breg:32|s0:8|s1:8] -> retire breg+s0 -> vmcnt(8)
//   it1: [s1:8|st0:8|s2:8]   -> vmcnt(16)
//   it2: [s2:8|st1:8|s3:8]   -> vmcnt(16)
//   it3: [s3:8|st2:8(+8 out2 at l=2047)] -> vmcnt(8)
__global__ __launch_bounds__(256, 2) void vaw_swap_kernel(
        const float* __restrict__ A, const short* __restrict__ Wt,
        float* __restrict__ out) {
    __shared__ __align__(16) float aLds[2][B_ * E_];   // 2 x 32 KB

    const int g_    = blockIdx.x;
    const int s     = g_ / NCH;
    const int chunk = g_ % NCH;
    const int cnt   = (s < 8) ? 103 : 102;   // #{l < 2048 : l % 20 == s}
    const int wv    = threadIdx.x >> 6;
    const int lane  = threadIdx.x & 63;
    const int r     = lane & 15;
    const int g     = lane >> 4;
    const int nbase = wv * 64;
    const int key   = r & 7;                 // (r+16)&7 == r&7

    // ---- B first: breg[kk][nf], 32 x 16B loads (L2/L3-resident Wt).
    const short* wtb = Wt + ((size_t)s * H_ + nbase + r) * E_ + g * 8;
    bf16x8 breg[8][4];
#pragma unroll
    for (int kk = 0; kk < 8; ++kk)
#pragma unroll
        for (int nf = 0; nf < 4; ++nf)
            breg[kk][nf] = *(const bf16x8*)(wtb + (size_t)nf * 16 * E_ + kk * 32);

    auto lof = [&](int il) {
        int idx = chunk * NL + il;
        if (idx > cnt - 1) idx = cnt - 1;    // tail clamp: duplicate work, benign
        return s + 20 * idx;
    };

    // Stage A-tile for iter it into aLds[it&1]: wave wv stages rows t*4+wv
    // (8 x 1KB); lane covers 16B chunk `lane^(row&7)` of the row (inverse-
    // swizzled global source, linear LDS dest).
    auto stage = [&](int it) {
        const int l = lof(it);
        float* dst = aLds[it & 1];
#pragma unroll
        for (int t = 0; t < 8; ++t) {
            const int b  = t * 4 + wv;
            const int cg = lane ^ (b & 7);
            const float* gp = A + ((size_t)b * L_ + l) * E_ + cg * 4;
            __builtin_amdgcn_global_load_lds(
                (const __attribute__((address_space(1))) void*)gp,
                (__attribute__((address_space(3))) void*)&dst[b * 256],
                16, 0, 0);
        }
    };

    stage(0);   // prologue

#pragma unroll 1
    for (int it = 0; it < NL; ++it) {
        const int l   = lof(it);
        const int cur = it & 1;

        if (it < NL - 1) stage(it + 1);

        if (it == 0)          asm volatile("s_waitcnt vmcnt(8)"  ::: "memory");
        else if (it < NL - 1) asm volatile("s_waitcnt vmcnt(16)" ::: "memory");
        else                  asm volatile("s_waitcnt vmcnt(8)"  ::: "memory");
        __builtin_amdgcn_s_barrier();        // all waves' stage(it) landed
        __builtin_amdgcn_sched_barrier(0);

        // acc[nf][half]: nf = h-frag (16 h's), half = b-half (a0: b=r, a1: b=r+16)
        f32x4 acc[4][2];
#pragma unroll
        for (int nf = 0; nf < 4; ++nf)
#pragma unroll
            for (int hf = 0; hf < 2; ++hf)
                acc[nf][hf] = f32x4{0.f, 0.f, 0.f, 0.f};

#pragma unroll
        for (int kk = 0; kk < 8; ++kk) {
            const int c0 = kk * 8 + g * 2;
            f32x4 a0lo = *(const f32x4*)&aLds[cur][r * 256 + ((c0 ^ key) << 2)];
            f32x4 a0hi = *(const f32x4*)&aLds[cur][r * 256 + (((c0 + 1) ^ key) << 2)];
            f32x4 a1lo = *(const f32x4*)&aLds[cur][(r + 16) * 256 + ((c0 ^ key) << 2)];
            f32x4 a1hi = *(const f32x4*)&aLds[cur][(r + 16) * 256 + (((c0 + 1) ^ key) << 2)];
            bf16x8 a0, a1;
#pragma unroll
            for (int j = 0; j < 4; ++j) {
                a0[j]     = cvt1(a0lo[j]);
                a0[j + 4] = cvt1(a0hi[j]);
                a1[j]     = cvt1(a1lo[j]);
                a1[j + 4] = cvt1(a1hi[j]);
            }
            // swapped operands: W^T as A-op, word_rep as B-op -> out^T frags
#pragma unroll
            for (int nf = 0; nf < 4; ++nf) {
                acc[nf][0] = __builtin_amdgcn_mfma_f32_16x16x32_bf16(breg[kk][nf], a0, acc[nf][0], 0, 0, 0);
                acc[nf][1] = __builtin_amdgcn_mfma_f32_16x16x32_bf16(breg[kk][nf], a1, acc[nf][1], 0, 0, 0);
            }
        }

        // Coalesced epilogue: one dwordx4 per (nf, half) = 8 stores.
#pragma unroll
        for (int hf = 0; hf < 2; ++hf) {
            const int b = r + 16 * hf;
            float* orow = out + ((size_t)b * L_ + l) * H_ + nbase + g * 4;
#pragma unroll
            for (int nf = 0; nf < 4; ++nf)
                *(f32x4*)(orow + nf * 16) = acc[nf][hf];
        }
        if (l == L_ - 1) {
            float* out2 = out + (size_t)B_ * L_ * H_;
#pragma unroll
            for (int hf = 0; hf < 2; ++hf) {
                const int b = r + 16 * hf;
                float* orow = out2 + (size_t)b * H_ + nbase + g * 4;
#pragma unroll
                for (int nf = 0; nf < 4; ++nf)
                    *(f32x4*)(orow + nf * 16) = acc[nf][hf];
            }
        }

        __builtin_amdgcn_s_barrier();   // reads of buf[cur] done before overwrite
    }
}

// Fallback (no workspace): round-5 structure, B from fp32 cnn per k-step.
__global__ __launch_bounds__(256) void vaw_fallback_kernel(
        const float* __restrict__ A, const float* __restrict__ W, float* __restrict__ out) {
    __shared__ __align__(16) float aLds[2][B_ * E_];
    const int l0   = blockIdx.x * 4;
    const int wv   = threadIdx.x >> 6;
    const int lane = threadIdx.x & 63;
    const int r    = lane & 15;
    const int g    = lane >> 4;
    const int nbase = wv * 64;
    const int key   = r & 7;

    auto stage = [&](int it) {
        float* dst = aLds[it & 1];
        const int l = l0 + it;
#pragma unroll
        for (int t = 0; t < 8; ++t) {
            const int b  = t * 4 + wv;
            const int cgx = lane ^ (b & 7);
            const float* gp = A + ((size_t)b * L_ + l) * E_ + cgx * 4;
            __builtin_amdgcn_global_load_lds(
                (const __attribute__((address_space(1))) void*)gp,
                (__attribute__((address_space(3))) void*)&dst[b * 256],
                16, 0, 0);
        }
    };

    stage(0);
#pragma unroll 1
    for (int it = 0; it < 4; ++it) {
        const int l   = l0 + it;
        const int sidx = l % MAXSTEP;
        const int cur = it & 1;
        if (it < 3) {
            stage(it + 1);
            asm volatile("s_waitcnt vmcnt(8)" ::: "memory");
        } else {
            asm volatile("s_waitcnt vmcnt(0)" ::: "memory");
        }
        __builtin_amdgcn_s_barrier();
        __builtin_amdgcn_sched_barrier(0);

        f32x4 acc[2][4] = {};
        const float* Wf = W + (size_t)sidx * E_ * H_;
#pragma unroll 2
        for (int kk = 0; kk < 8; ++kk) {
            const int k0 = kk * 32;
            const int c0 = kk * 8 + g * 2;
            f32x4 a0lo = *(const f32x4*)&aLds[cur][r * 256 + ((c0 ^ key) << 2)];
            f32x4 a0hi = *(const f32x4*)&aLds[cur][r * 256 + (((c0 + 1) ^ key) << 2)];
            f32x4 a1lo = *(const f32x4*)&aLds[cur][(r + 16) * 256 + ((c0 ^ key) << 2)];
            f32x4 a1hi = *(const f32x4*)&aLds[cur][(r + 16) * 256 + (((c0 + 1) ^ key) << 2)];
            bf16x8 a0, a1;
#pragma unroll
            for (int j = 0; j < 4; ++j) {
                a0[j]     = cvt1(a0lo[j]);
                a0[j + 4] = cvt1(a0hi[j]);
                a1[j]     = cvt1(a1lo[j]);
                a1[j + 4] = cvt1(a1hi[j]);
            }
            bf16x8 b0, b1, b2, b3;
#pragma unroll
            for (int j = 0; j < 8; ++j) {
                const size_t krow = (size_t)(k0 + g * 8 + j) * H_;
                b0[j] = cvt1(Wf[krow + nbase +  0 + r]);
                b1[j] = cvt1(Wf[krow + nbase + 16 + r]);
                b2[j] = cvt1(Wf[krow + nbase + 32 + r]);
                b3[j] = cvt1(Wf[krow + nbase + 48 + r]);
            }
            acc[0][0] = __builtin_amdgcn_mfma_f32_16x16x32_bf16(a0, b0, acc[0][0], 0, 0, 0);
            acc[0][1] = __builtin_amdgcn_mfma_f32_16x16x32_bf16(a0, b1, acc[0][1], 0, 0, 0);
            acc[0][2] = __builtin_amdgcn_mfma_f32_16x16x32_bf16(a0, b2, acc[0][2], 0, 0, 0);
            acc[0][3] = __builtin_amdgcn_mfma_f32_16x16x32_bf16(a0, b3, acc[0][3], 0, 0, 0);
            acc[1][0] = __builtin_amdgcn_mfma_f32_16x16x32_bf16(a1, b0, acc[1][0], 0, 0, 0);
            acc[1][1] = __builtin_amdgcn_mfma_f32_16x16x32_bf16(a1, b1, acc[1][1], 0, 0, 0);
            acc[1][2] = __builtin_amdgcn_mfma_f32_16x16x32_bf16(a1, b2, acc[1][2], 0, 0, 0);
            acc[1][3] = __builtin_amdgcn_mfma_f32_16x16x32_bf16(a1, b3, acc[1][3], 0, 0, 0);
        }

        const int row0 = g * 4;
#pragma unroll
        for (int mf = 0; mf < 2; ++mf)
#pragma unroll
            for (int nf = 0; nf < 4; ++nf) {
                const int h = nbase + nf * 16 + r;
#pragma unroll
                for (int i = 0; i < 4; ++i) {
                    const int bb = mf * 16 + row0 + i;
                    out[((size_t)bb * L_ + l) * H_ + h] = acc[mf][nf][i];
                }
            }
        if (l == L_ - 1) {
            float* out2 = out + (size_t)B_ * L_ * H_;
#pragma unroll
            for (int mf = 0; mf < 2; ++mf)
#pragma unroll
                for (int nf = 0; nf < 4; ++nf) {
                    const int h = nbase + nf * 16 + r;
#pragma unroll
                    for (int i = 0; i < 4; ++i) {
                        const int bb = mf * 16 + row0 + i;
                        out2[(size_t)bb * H_ + h] = acc[mf][nf][i];
                    }
                }
        }
        __builtin_amdgcn_s_barrier();
    }
}

extern "C" void kernel_launch(void* const* d_in, const int* in_sizes, int n_in,
                              void* d_out, int out_size, void* d_ws, size_t ws_size,
                              hipStream_t stream) {
    const float* word_rep = (const float*)d_in[0];
    const float* cnn      = (const float*)d_in[1];
    float* out = (float*)d_out;

    const size_t wt_bytes = (size_t)MAXSTEP * E_ * H_ * sizeof(short);
    if (ws_size >= wt_bytes) {
        short* wt = (short*)d_ws;
        transpose_w_kernel<<<dim3(8, 8, 20), dim3(32, 8), 0, stream>>>(cnn, wt);
        vaw_swap_kernel<<<dim3(NGRP), dim3(256), 0, stream>>>(word_rep, wt, out);
    } else {
        vaw_fallback_kernel<<<dim3(L_ / 4), dim3(256), 0, stream>>>(word_rep, cnn, out);
    }
}